// Round 7
// baseline (256.278 us; speedup 1.0000x reference)
//
#include <hip/hip_runtime.h>
#include <stdint.h>

// Problem constants (B,T,J,D) = (64, 2048, 128, 256)
#define Bb 64
#define Tt 2048
#define Jj 128
#define Dd 256

// R12 = R11 + correct allocator directive. R11 post-mortem: VGPR_Count=64
// with ~120 live -> the allocator spilled the depth-8 prefetch to scratch
// (WRITE_SIZE 151 MB vs 67 MB ideal = ~320 B/thread of spill stores; kernel
// 95.8 us). (512,4) only sets MIN waves/EU, so the allocator squeezed to 64
// VGPR chasing 8 waves/EU -- pointless, since LDS (72.5 KB) caps us at
// 2 blocks/CU (4 waves/EU) for any VGPR <= 128. This also invalidates
// R9/R10's null: depth-6 also ran through scratch, never registers.
// Fix: amdgpu_waves_per_eu(4,4) -- min AND max 4 -> budget exactly 128,
// no incentive to squeeze; ~120 live regs stay in the file.
//
// Structure (R11, verified): full-m-tile depth-8 H prefetch (issue all 16
// loads as one DRAM-friendly burst; refill mt=1 one pair/step during mt=0),
// row-per-wave single-pass U (builds verified lUp layout + lane-local s_u,
// single barrier), 9 B-tiles in LDS (8 j-tiles + w1 column for s_h-via-MFMA),
// A-frag pack8, C/D col=lane&15 row=quad*4+reg epilogue, XCD swizzle.

typedef __attribute__((ext_vector_type(8))) __bf16 bf16x8;
typedef __attribute__((ext_vector_type(8))) unsigned short ushort8v;
typedef __attribute__((ext_vector_type(4))) float f32x4;

__device__ __forceinline__ unsigned short f2bf(float f) {
    unsigned int u = __builtin_bit_cast(unsigned int, f);
    u += 0x7FFFu + ((u >> 16) & 1u);
    return (unsigned short)(u >> 16);
}

__device__ __forceinline__ bf16x8 pack8(const float4& a0, const float4& a1) {
    bf16x8 r;
    r[0] = (__bf16)a0.x; r[1] = (__bf16)a0.y; r[2] = (__bf16)a0.z; r[3] = (__bf16)a0.w;
    r[4] = (__bf16)a1.x; r[5] = (__bf16)a1.y; r[6] = (__bf16)a1.z; r[7] = (__bf16)a1.w;
    return r;
}

__global__ __launch_bounds__(512)
__attribute__((amdgpu_waves_per_eu(4, 4)))
void sim_fused(const float* __restrict__ H, const float* __restrict__ U,
               const float* __restrict__ w, float* __restrict__ out) {
    __shared__ ushort8v lUp[4608];   // 72 KB: tiles j=0..8, unit (j*8+ks)*64+lane
    __shared__ float    lsu[Jj];     // 512 B: s_u for this batch

    const int tid   = threadIdx.x;
    const int wid   = tid >> 6;
    const int lane  = tid & 63;
    const int row16 = lane & 15;
    const int quad  = lane >> 4;

    // Bijective XCD swizzle (assumed round-robin blockIdx->XCD): the 8 blocks
    // of batch b share one XCD's L2 for U[b].
    const int o     = blockIdx.x;
    const int b     = (o & 7) * 8 + ((o >> 3) & 7);
    const int mbase = (o >> 6) * 256;              // 8 m-tiles of 256 rows

    // ---- depth-8 H prefetch: issue the ENTIRE mt=0 A-tile as one burst ----
    // A-fragment layout: lane holds row mbase + mt*128 + wid*16 + row16,
    // k-slice ks covers floats [ks*32 + quad*8, +8).
    const float* Hbase = H + ((size_t)(b * Tt + mbase + wid * 16 + row16)) * Dd + quad * 8;
    float4 hb0[8], hb1[8];
#pragma unroll
    for (int p = 0; p < 8; ++p) {
        hb0[p] = *(const float4*)(Hbase + p * 32);
        hb1[p] = *(const float4*)(Hbase + p * 32 + 4);
    }

    // ---- U pass, row-per-wave: wave wid owns rows wid*16+row16, all k ----
    // Builds lUp[(wid*8+p)*64+lane] (identical bytes/layout as R10's build)
    // and a fully lane-local s_u partial.
    const float* Urow = U + ((size_t)(b * Jj + wid * 16 + row16)) * Dd + quad * 8;
    float sup = 0.f;
#pragma unroll
    for (int p = 0; p < 8; ++p) {
        const float4 u0 = *(const float4*)(Urow + p * 32);
        const float4 u1 = *(const float4*)(Urow + p * 32 + 4);
        const float* w3p = w + 2 * Dd + p * 32 + quad * 8;
        const float4 w30 = *(const float4*)(w3p);
        const float4 w31 = *(const float4*)(w3p + 4);
        const float* w2p = w + Dd + p * 32 + quad * 8;
        const float4 w20 = *(const float4*)(w2p);
        const float4 w21 = *(const float4*)(w2p + 4);
        ushort8v s;
        s[0] = f2bf(u0.x * w30.x); s[1] = f2bf(u0.y * w30.y);
        s[2] = f2bf(u0.z * w30.z); s[3] = f2bf(u0.w * w30.w);
        s[4] = f2bf(u1.x * w31.x); s[5] = f2bf(u1.y * w31.y);
        s[6] = f2bf(u1.z * w31.z); s[7] = f2bf(u1.w * w31.w);
        lUp[(wid * 8 + p) * 64 + lane] = s;
        sup += u0.x * w20.x + u0.y * w20.y + u0.z * w20.z + u0.w * w20.w
             + u1.x * w21.x + u1.y * w21.y + u1.z * w21.z + u1.w * w21.w;
    }
    {   // tile 8: w1-column, B[n][k] = (n==0) ? w1[k] : 0  (slice ks = wid)
        const int k0 = wid * 32 + quad * 8;
        const float4 w1a = *(const float4*)(w + k0);
        const float4 w1b = *(const float4*)(w + k0 + 4);
        const bool n0 = row16 == 0;
        ushort8v s;
        s[0] = n0 ? f2bf(w1a.x) : (unsigned short)0;
        s[1] = n0 ? f2bf(w1a.y) : (unsigned short)0;
        s[2] = n0 ? f2bf(w1a.z) : (unsigned short)0;
        s[3] = n0 ? f2bf(w1a.w) : (unsigned short)0;
        s[4] = n0 ? f2bf(w1b.x) : (unsigned short)0;
        s[5] = n0 ? f2bf(w1b.y) : (unsigned short)0;
        s[6] = n0 ? f2bf(w1b.z) : (unsigned short)0;
        s[7] = n0 ? f2bf(w1b.w) : (unsigned short)0;
        lUp[(8 * 8 + wid) * 64 + lane] = s;
    }
    // quad-reduce: lanes {r, r+16, r+32, r+48} hold the 4 k-quarters of row r
    sup += __shfl_xor(sup, 16);
    sup += __shfl_xor(sup, 32);
    if (lane < 16) lsu[wid * 16 + lane] = sup;    // quad==0, row16==lane

    f32x4 acc[9];
#pragma unroll
    for (int j = 0; j < 9; ++j) acc[j] = (f32x4){0.f, 0.f, 0.f, 0.f};

    __syncthreads();

    // ---- main loop: 2 m-tiles x 8 ks; slot == ks (full-tile registers) ----
#pragma unroll
    for (int mt = 0; mt < 2; ++mt) {
#pragma unroll
        for (int ks = 0; ks < 8; ++ks) {
            const float4 h0 = hb0[ks];
            const float4 h1 = hb1[ks];
            if (mt == 0) {   // static: refill this slot with mt=1's slice
                const float* np = Hbase + (size_t)(128 * Dd) + ks * 32;
                hb0[ks] = *(const float4*)(np);
                hb1[ks] = *(const float4*)(np + 4);
            }

            const bf16x8 af = pack8(h0, h1);
#pragma unroll
            for (int j = 0; j < 9; ++j) {
                const bf16x8 bf = __builtin_bit_cast(bf16x8, lUp[(j * 8 + ks) * 64 + lane]);
                acc[j] = __builtin_amdgcn_mfma_f32_16x16x32_bf16(af, bf, acc[j], 0, 0, 0);
            }
        }

        // epilogue for this m-tile
        // s_h for output row quad*4+rg lives in lane quad*16 (col 0) of acc[8]
        float shv[4];
#pragma unroll
        for (int rg = 0; rg < 4; ++rg)
            shv[rg] = __shfl(acc[8][rg], quad * 16);

        float* outW = out + ((size_t)(b * Tt + mbase + mt * 128 + wid * 16)) * Jj;
#pragma unroll
        for (int j = 0; j < 8; ++j) {
            const int col = j * 16 + row16;
            const float suv = lsu[col];
#pragma unroll
            for (int rg = 0; rg < 4; ++rg)
                outW[(size_t)(quad * 4 + rg) * Jj + col] = acc[j][rg] + shv[rg] + suv;
        }

        if (mt == 0) {
#pragma unroll
            for (int j = 0; j < 9; ++j) acc[j] = (f32x4){0.f, 0.f, 0.f, 0.f};
        }
    }
}

extern "C" void kernel_launch(void* const* d_in, const int* in_sizes, int n_in,
                              void* d_out, int out_size, void* d_ws, size_t ws_size,
                              hipStream_t stream) {
    const float* H = (const float*)d_in[0];
    const float* U = (const float*)d_in[1];
    const float* w = (const float*)d_in[2];
    float* out = (float*)d_out;
    (void)d_ws; (void)ws_size;

    sim_fused<<<Bb * 8, 512, 0, stream>>>(H, U, w, out);
}

// Round 8
// 248.976 us; speedup vs baseline: 1.0293x; 1.0293x over previous
//
#include <hip/hip_runtime.h>
#include <stdint.h>

// Problem constants (B,T,J,D) = (64, 2048, 128, 256)
#define Bb 64
#define Tt 2048
#define Jj 128
#define Dd 256

// R13: occupancy split. Evidence chain: arch-VGPR allocation pins at ~64
// (R7=60 clean; R11/R12=64 + 84MB spill despite waves_per_eu(4,4)); clean
// configs (R8) sit at ~72 us kernel vs ~33 us HBM-bus floor with all pipes
// <10% -> bus 43% utilized, 16 waves/CU (LDS-capped at 2 blocks x 72.5 KB).
// Fix: j-split. Block = 256 rows x 64 cols:
//  - LDS = 4 B-tiles (32 KB) + 512 B s_u scratch -> 3-4 blocks/CU (24-32
//    waves). H is read by the 2 j-half blocks, which are placed on the SAME
//    XCD (swizzle) -> second read is L2/L3-served (R11/R12 FETCH=116MB<134MB
//    proves L3 absorbs re-reads).
//  - s_h via 8 VALU FMAs/step on the fp32 h regs (w1 slices L1-hot, 3 KB),
//    replacing the 9th MFMA tile -> no 8 KB w1 tile, fp32-exact s_h.
//  - acc[4] (16 acc regs); arch-live ~50 everywhere -> no spill at the
//    empirical 64-arch cap. Depth-2 rolling H prefetch (TLP covers BW:
//    24+ waves x 2 KB in flight >> 9 KB/CU needed).
//  - U-pass: wave wid builds tile j=wid&3, k-half kh=wid>>2 (4 units);
//    s_u partials quad-reduced then summed across the 2 k-halves via lsuP.
// Verified machinery unchanged (R1-R12): lUp unit layout (j*8+ks)*64+lane,
// f2bf Up', pack8 A-frag, C/D col=lane&15 row=quad*4+reg epilogue.

typedef __attribute__((ext_vector_type(8))) __bf16 bf16x8;
typedef __attribute__((ext_vector_type(8))) unsigned short ushort8v;
typedef __attribute__((ext_vector_type(4))) float f32x4;

__device__ __forceinline__ unsigned short f2bf(float f) {
    unsigned int u = __builtin_bit_cast(unsigned int, f);
    u += 0x7FFFu + ((u >> 16) & 1u);
    return (unsigned short)(u >> 16);
}

__device__ __forceinline__ bf16x8 pack8(const float4& a0, const float4& a1) {
    bf16x8 r;
    r[0] = (__bf16)a0.x; r[1] = (__bf16)a0.y; r[2] = (__bf16)a0.z; r[3] = (__bf16)a0.w;
    r[4] = (__bf16)a1.x; r[5] = (__bf16)a1.y; r[6] = (__bf16)a1.z; r[7] = (__bf16)a1.w;
    return r;
}

__global__ __launch_bounds__(512)
void sim_fused(const float* __restrict__ H, const float* __restrict__ U,
               const float* __restrict__ w, float* __restrict__ out) {
    __shared__ ushort8v lUp[2048];   // 32 KB: tiles j=0..3, unit (j*8+ks)*64+lane
    __shared__ float    lsuP[128];   // 512 B: s_u partials, [kh*64 + col]

    const int tid   = threadIdx.x;
    const int wid   = tid >> 6;
    const int lane  = tid & 63;
    const int row16 = lane & 15;
    const int quad  = lane >> 4;

    // Bijective XCD swizzle over 1024 blocks (assumed round-robin o->XCD):
    // XCD x gets batches 8x..8x+7; both j-halves of the same rows land on
    // the same XCD so the duplicate H read is L2-served.
    const int o     = blockIdx.x;
    const int b     = (o & 7) * 8 + ((o >> 3) & 7);
    const int jh    = (o >> 6) & 1;                // j-half: cols jh*64..+63
    const int mbase = (o >> 7) * 256;              // 8 m-blocks of 256 rows

    // ---- depth-2 rolling H prefetch (A-frag: lane = row mbase+mt*128+
    // wid*16+row16, k-octet quad*8; flattened kk: +(kk>>3)*128*Dd+(kk&7)*32)
    const float* Hbase = H + ((size_t)(b * Tt + mbase + wid * 16 + row16)) * Dd + quad * 8;
    float4 hb0[2], hb1[2];
#pragma unroll
    for (int p = 0; p < 2; ++p) {
        hb0[p] = *(const float4*)(Hbase + p * 32);
        hb1[p] = *(const float4*)(Hbase + p * 32 + 4);
    }

    // ---- U pass: wave wid builds tile uj = wid&3, k-half kh = wid>>2 ----
    const int uj = wid & 3;
    const int kh = wid >> 2;
    const float* Urow = U + ((size_t)(b * Jj + jh * 64 + uj * 16 + row16)) * Dd
                        + kh * 128 + quad * 8;
    float sup = 0.f;
#pragma unroll
    for (int p = 0; p < 4; ++p) {
        const float4 u0 = *(const float4*)(Urow + p * 32);
        const float4 u1 = *(const float4*)(Urow + p * 32 + 4);
        const float* w3p = w + 2 * Dd + kh * 128 + p * 32 + quad * 8;
        const float4 w30 = *(const float4*)(w3p);
        const float4 w31 = *(const float4*)(w3p + 4);
        const float* w2p = w + Dd + kh * 128 + p * 32 + quad * 8;
        const float4 w20 = *(const float4*)(w2p);
        const float4 w21 = *(const float4*)(w2p + 4);
        ushort8v s;
        s[0] = f2bf(u0.x * w30.x); s[1] = f2bf(u0.y * w30.y);
        s[2] = f2bf(u0.z * w30.z); s[3] = f2bf(u0.w * w30.w);
        s[4] = f2bf(u1.x * w31.x); s[5] = f2bf(u1.y * w31.y);
        s[6] = f2bf(u1.z * w31.z); s[7] = f2bf(u1.w * w31.w);
        lUp[(uj * 8 + kh * 4 + p) * 64 + lane] = s;
        sup += u0.x * w20.x + u0.y * w20.y + u0.z * w20.z + u0.w * w20.w
             + u1.x * w21.x + u1.y * w21.y + u1.z * w21.z + u1.w * w21.w;
    }
    // lanes {r, r+16, r+32, r+48} hold the 4 k-octet groups of row uj*16+r
    sup += __shfl_xor(sup, 16);
    sup += __shfl_xor(sup, 32);
    if (lane < 16) lsuP[kh * 64 + uj * 16 + lane] = sup;

    f32x4 acc[4];
#pragma unroll
    for (int j = 0; j < 4; ++j) acc[j] = (f32x4){0.f, 0.f, 0.f, 0.f};

    __syncthreads();

    // ---- main loop: 2 m-tiles x 8 ks; s_h via fp32 FMAs on h regs ----
#pragma unroll
    for (int mt = 0; mt < 2; ++mt) {
        float sh = 0.f;
#pragma unroll
        for (int ks = 0; ks < 8; ++ks) {
            const int kk   = mt * 8 + ks;
            const int slot = kk & 1;               // static under full unroll
            const float4 h0 = hb0[slot];
            const float4 h1 = hb1[slot];
            if (kk < 14) {                         // static: refill the slot
                const float* np = Hbase + (size_t)(((kk + 2) >> 3) * 128 * Dd)
                                        + ((kk + 2) & 7) * 32;
                hb0[slot] = *(const float4*)(np);
                hb1[slot] = *(const float4*)(np + 4);
            }

            // s_h partial for row row16 (w1 slice is L1-hot, 3 KB total)
            const float* w1p = w + ks * 32 + quad * 8;
            const float4 wa = *(const float4*)(w1p);
            const float4 wb = *(const float4*)(w1p + 4);
            sh += h0.x * wa.x + h0.y * wa.y + h0.z * wa.z + h0.w * wa.w
                + h1.x * wb.x + h1.y * wb.y + h1.z * wb.z + h1.w * wb.w;

            const bf16x8 af = pack8(h0, h1);
#pragma unroll
            for (int j = 0; j < 4; ++j) {
                const bf16x8 bf = __builtin_bit_cast(bf16x8, lUp[(j * 8 + ks) * 64 + lane]);
                acc[j] = __builtin_amdgcn_mfma_f32_16x16x32_bf16(af, bf, acc[j], 0, 0, 0);
            }
        }

        // epilogue for this m-tile
        // full-row s_h: reduce the 4 quad partials of row row16
        float sh2 = sh;
        sh2 += __shfl_xor(sh2, 16);
        sh2 += __shfl_xor(sh2, 32);
        float shv[4];
#pragma unroll
        for (int rg = 0; rg < 4; ++rg)
            shv[rg] = __shfl(sh2, quad * 4 + rg);  // row (quad*4+rg)'s s_h

        float* outW = out + ((size_t)(b * Tt + mbase + mt * 128 + wid * 16)) * Jj + jh * 64;
#pragma unroll
        for (int j = 0; j < 4; ++j) {
            const int col = j * 16 + row16;
            const float suv = lsuP[col] + lsuP[64 + col];
#pragma unroll
            for (int rg = 0; rg < 4; ++rg)
                outW[(size_t)(quad * 4 + rg) * Jj + col] = acc[j][rg] + shv[rg] + suv;
        }

        if (mt == 0) {
#pragma unroll
            for (int j = 0; j < 4; ++j) acc[j] = (f32x4){0.f, 0.f, 0.f, 0.f};
        }
    }
}

extern "C" void kernel_launch(void* const* d_in, const int* in_sizes, int n_in,
                              void* d_out, int out_size, void* d_ws, size_t ws_size,
                              hipStream_t stream) {
    const float* H = (const float*)d_in[0];
    const float* U = (const float*)d_in[1];
    const float* w = (const float*)d_in[2];
    float* out = (float*)d_out;
    (void)d_ws; (void)ws_size;

    sim_fused<<<Bb * 16, 512, 0, stream>>>(H, U, w, out);
}